// Round 1
// baseline (723.996 us; speedup 1.0000x reference)
//
#include <hip/hip_runtime.h>
#include <hip/hip_bf16.h>

// Problem constants
#define VOCAB 10000
#define HID 256
#define BATCH 32
#define STEPS 256
#define MROWS (STEPS * BATCH)   // 8192

typedef __bf16 bf16x8 __attribute__((ext_vector_type(8)));
typedef float f32x4 __attribute__((ext_vector_type(4)));

// ---------------------------------------------------------------------------
// Kernel 1: transpose + convert W_d [256][10000] f32 -> WdT [10000][256] bf16
// 64x64 tiles through LDS so both global read and write stay coalesced.
// ---------------------------------------------------------------------------
__global__ void transpose_wd_kernel(const float* __restrict__ Wd,
                                    __hip_bfloat16* __restrict__ WdT) {
    __shared__ __hip_bfloat16 tile[64][68];  // +4 pad: 2-way max on writes
    const int n0 = blockIdx.x * 64;
    const int k0 = blockIdx.y * 64;
    const int tid = threadIdx.x;
    const int lane = tid & 63;
    const int w = tid >> 6;

#pragma unroll
    for (int i = 0; i < 16; ++i) {
        int k = w * 16 + i;          // 0..63, k0+k < 256 always (256 = 4*64)
        int n = lane;
        float v = (n0 + n < VOCAB) ? Wd[(size_t)(k0 + k) * VOCAB + n0 + n] : 0.f;
        tile[n][k] = __float2bfloat16(v);
    }
    __syncthreads();
#pragma unroll
    for (int i = 0; i < 16; ++i) {
        int n = w * 16 + i;
        int k = lane;
        if (n0 + n < VOCAB)
            WdT[(size_t)(n0 + n) * HID + k0 + k] = tile[n][k];
    }
}

// ---------------------------------------------------------------------------
// Kernel 2: gather + RNN recurrence, fp32.
// One block per batch element (32 blocks). Thread j owns column j of W_hh in
// registers; h lives in LDS and is read via broadcast float4 loads.
// Writes Y as bf16 [T][B][H] (time-major == output row-major) and final state
// as f32 to the tail of d_out.
// ---------------------------------------------------------------------------
__global__ __launch_bounds__(256, 1)
void rnn_kernel(const int* __restrict__ tokens, const float* __restrict__ Wxh,
                const float* __restrict__ Whh, const float* __restrict__ bh,
                const float* __restrict__ h0, __hip_bfloat16* __restrict__ ybf,
                float* __restrict__ state_out) {
    const int b = blockIdx.x;
    const int j = threadIdx.x;

    __shared__ alignas(16) float hbuf[HID];

    // Column j of W_hh into registers (coalesced per row).
    float w[HID];
#pragma unroll
    for (int i = 0; i < HID; ++i) w[i] = Whh[i * HID + j];

    hbuf[j] = h0[b * HID + j];
    const float bj = bh[j];
    const int* trow = tokens + b * STEPS;

    int tok0 = trow[0];
    float x = Wxh[(size_t)tok0 * HID + j];
    __syncthreads();

    float hn = 0.f;
    for (int t = 0; t < STEPS; ++t) {
        // Prefetch next step's gathered x to hide HBM latency under the dot.
        float xn = 0.f;
        if (t < STEPS - 1) {
            int tk = trow[t + 1];
            xn = Wxh[(size_t)tk * HID + j];
        }

        float a0 = 0.f, a1 = 0.f, a2 = 0.f, a3 = 0.f;
#pragma unroll
        for (int i4 = 0; i4 < HID / 4; ++i4) {
            float4 hv = *reinterpret_cast<const float4*>(&hbuf[i4 * 4]);
            a0 += hv.x * w[i4 * 4 + 0];
            a1 += hv.y * w[i4 * 4 + 1];
            a2 += hv.z * w[i4 * 4 + 2];
            a3 += hv.w * w[i4 * 4 + 3];
        }
        hn = tanhf(x + bj + ((a0 + a1) + (a2 + a3)));

        ybf[(size_t)t * (BATCH * HID) + b * HID + j] = __float2bfloat16(hn);

        __syncthreads();           // everyone done reading old h
        hbuf[j] = hn;
        __syncthreads();           // new h visible
        x = xn;
    }
    state_out[b * HID + j] = hn;   // h_{T-1}
}

// ---------------------------------------------------------------------------
// Kernel 3: C[8192][10000] = Y_bf16 @ Wd^T_bf16 + b_d, f32 out.
// 128x128 tile, BK=64, 4 waves (2x2), each wave 64x64 via 4x4 16x16x32 MFMAs.
// LDS rows padded +8 bf16 (row stride 144B = 16B-aligned, ~2-way banks).
// ---------------------------------------------------------------------------
__global__ void gemm_kernel(const __hip_bfloat16* __restrict__ A,   // [8192][256]
                            const __hip_bfloat16* __restrict__ BT,  // [10000][256]
                            const float* __restrict__ bd,
                            float* __restrict__ C) {
    const int n0 = blockIdx.x * 128;
    const int m0 = blockIdx.y * 128;
    const int tid = threadIdx.x;
    const int lane = tid & 63;
    const int wv = tid >> 6;
    const int wr = wv >> 1;      // wave row (0..1)
    const int wc = wv & 1;       // wave col (0..1)
    const int r15 = lane & 15;
    const int g = lane >> 4;     // 0..3

    __shared__ alignas(16) __hip_bfloat16 As[128][72];
    __shared__ alignas(16) __hip_bfloat16 Bs[128][72];

    f32x4 acc[4][4] = {};

    for (int kb = 0; kb < HID; kb += 64) {
        __syncthreads();
        // Stage A and B tiles: 1024 16B-chunks each, 4 per thread.
#pragma unroll
        for (int c = 0; c < 4; ++c) {
            int chunk = c * 256 + tid;    // 0..1023
            int row = chunk >> 3;         // 0..127
            int cc = chunk & 7;           // 16B chunk within 64 elems
            bf16x8 av = *reinterpret_cast<const bf16x8*>(
                &A[(size_t)(m0 + row) * HID + kb + cc * 8]);
            *reinterpret_cast<bf16x8*>(&As[row][cc * 8]) = av;

            int nrow = n0 + row;
            bf16x8 bv;
#pragma unroll
            for (int e = 0; e < 8; ++e) bv[e] = (__bf16)0.f;
            if (nrow < VOCAB)
                bv = *reinterpret_cast<const bf16x8*>(
                    &BT[(size_t)nrow * HID + kb + cc * 8]);
            *reinterpret_cast<bf16x8*>(&Bs[row][cc * 8]) = bv;
        }
        __syncthreads();

#pragma unroll
        for (int kk = 0; kk < 64; kk += 32) {
            bf16x8 af[4], bfr[4];
#pragma unroll
            for (int m = 0; m < 4; ++m)
                af[m] = *reinterpret_cast<const bf16x8*>(
                    &As[wr * 64 + m * 16 + r15][kk + g * 8]);
#pragma unroll
            for (int n = 0; n < 4; ++n)
                bfr[n] = *reinterpret_cast<const bf16x8*>(
                    &Bs[wc * 64 + n * 16 + r15][kk + g * 8]);
#pragma unroll
            for (int m = 0; m < 4; ++m)
#pragma unroll
                for (int n = 0; n < 4; ++n)
                    acc[m][n] = __builtin_amdgcn_mfma_f32_16x16x32_bf16(
                        af[m], bfr[n], acc[m][n], 0, 0, 0);
        }
    }

    // Epilogue: C/D layout col = lane&15, row = 4*(lane>>4) + reg.
#pragma unroll
    for (int m = 0; m < 4; ++m) {
        int rowb = m0 + wr * 64 + m * 16 + g * 4;
#pragma unroll
        for (int n = 0; n < 4; ++n) {
            int col = n0 + wc * 64 + n * 16 + r15;
            if (col < VOCAB) {
                float bias = bd[col];
#pragma unroll
                for (int r = 0; r < 4; ++r) {
                    C[(size_t)(rowb + r) * VOCAB + col] = acc[m][n][r] + bias;
                }
            }
        }
    }
}

// ---------------------------------------------------------------------------
extern "C" void kernel_launch(void* const* d_in, const int* in_sizes, int n_in,
                              void* d_out, int out_size, void* d_ws, size_t ws_size,
                              hipStream_t stream) {
    const int* tokens  = (const int*)d_in[0];
    const float* Wxh   = (const float*)d_in[1];
    const float* Whh   = (const float*)d_in[2];
    const float* bh    = (const float*)d_in[3];
    const float* Wd    = (const float*)d_in[4];
    const float* bd    = (const float*)d_in[5];
    const float* h0    = (const float*)d_in[6];

    float* out = (float*)d_out;
    float* state_out = out + (size_t)MROWS * VOCAB;   // tuple part 2

    // Workspace: Y bf16 [8192][256] (4 MB) then WdT bf16 [10000][256] (5 MB)
    __hip_bfloat16* ybf = (__hip_bfloat16*)d_ws;
    __hip_bfloat16* wdt = (__hip_bfloat16*)((char*)d_ws + (size_t)MROWS * HID * 2);

    hipLaunchKernelGGL(transpose_wd_kernel, dim3(157, 4), dim3(256), 0, stream,
                       Wd, wdt);
    hipLaunchKernelGGL(rnn_kernel, dim3(BATCH), dim3(256), 0, stream,
                       tokens, Wxh, Whh, bh, h0, ybf, state_out);
    hipLaunchKernelGGL(gemm_kernel, dim3(79, 64), dim3(256), 0, stream,
                       ybf, wdt, bd, out);
}

// Round 2
// 410.804 us; speedup vs baseline: 1.7624x; 1.7624x over previous
//
#include <hip/hip_runtime.h>
#include <hip/hip_bf16.h>

// Problem constants
#define VOCAB 10000
#define HID 256
#define BATCH 32
#define STEPS 256
#define MROWS (STEPS * BATCH)   // 8192

typedef __bf16 bf16x8 __attribute__((ext_vector_type(8)));
typedef float f32x4 __attribute__((ext_vector_type(4)));

// ---------------------------------------------------------------------------
// Kernel 1: transpose + convert W_d [256][10000] f32 -> WdT [10000][256] bf16
// ---------------------------------------------------------------------------
__global__ void transpose_wd_kernel(const float* __restrict__ Wd,
                                    __hip_bfloat16* __restrict__ WdT) {
    __shared__ __hip_bfloat16 tile[64][68];
    const int n0 = blockIdx.x * 64;
    const int k0 = blockIdx.y * 64;
    const int tid = threadIdx.x;
    const int lane = tid & 63;
    const int w = tid >> 6;

#pragma unroll
    for (int i = 0; i < 16; ++i) {
        int k = w * 16 + i;
        int n = lane;
        float v = (n0 + n < VOCAB) ? Wd[(size_t)(k0 + k) * VOCAB + n0 + n] : 0.f;
        tile[n][k] = __float2bfloat16(v);
    }
    __syncthreads();
#pragma unroll
    for (int i = 0; i < 16; ++i) {
        int n = w * 16 + i;
        int k = lane;
        if (n0 + n < VOCAB)
            WdT[(size_t)(n0 + n) * HID + k0 + k] = tile[n][k];
    }
}

// ---------------------------------------------------------------------------
// Kernel 2: gather + RNN recurrence, fp32.
// 32 blocks (one per batch) x 512 threads. Thread (j = tid>>1, q = tid&1)
// owns half of W_hh column j in registers (128 VGPRs -> NO spill, unlike the
// previous 256-float version that spilled to scratch at VGPR_Count=140).
// h double-buffered in LDS -> ONE barrier per step. Pair-reduce via shfl_xor.
// ---------------------------------------------------------------------------
__global__ __launch_bounds__(512, 2)
void rnn_kernel(const int* __restrict__ tokens, const float* __restrict__ Wxh,
                const float* __restrict__ Whh, const float* __restrict__ bh,
                const float* __restrict__ h0, __hip_bfloat16* __restrict__ ybf,
                float* __restrict__ state_out) {
    const int b = blockIdx.x;
    const int tid = threadIdx.x;
    const int j = tid >> 1;      // output column 0..255
    const int q = tid & 1;       // k-half

    __shared__ alignas(16) float hbuf[2][HID];

    // Half-column of W_hh into registers: w[i] = Whh[q*128 + i][j].
    float w[128];
#pragma unroll
    for (int i = 0; i < 128; ++i)
        w[i] = Whh[(size_t)(q * 128 + i) * HID + j];

    if (q == 0) hbuf[0][j] = h0[b * HID + j];
    const float bj = bh[j];
    const int* trow = tokens + b * STEPS;

    // Prefetch step-0 gathered x.
    float x = Wxh[(size_t)trow[0] * HID + j];
    __syncthreads();

    float hn = 0.f;
    int cur = 0;
    for (int t = 0; t < STEPS; ++t) {
        // Prefetch next step's x (hidden under the dot product).
        float xn = 0.f;
        if (t + 1 < STEPS)
            xn = Wxh[(size_t)trow[t + 1] * HID + j];

        // Partial dot over this thread's k-half. LDS reads are 2-address
        // broadcasts (even/odd lanes 512B apart -> same bank, 2-way = free).
        const float* hrow = &hbuf[cur][q * 128];
        float a0 = 0.f, a1 = 0.f, a2 = 0.f, a3 = 0.f;
#pragma unroll
        for (int i4 = 0; i4 < 32; ++i4) {
            float4 hv = *reinterpret_cast<const float4*>(&hrow[i4 * 4]);
            a0 += hv.x * w[i4 * 4 + 0];
            a1 += hv.y * w[i4 * 4 + 1];
            a2 += hv.z * w[i4 * 4 + 2];
            a3 += hv.w * w[i4 * 4 + 3];
        }
        float partial = (a0 + a1) + (a2 + a3);
        float sum = partial + __shfl_xor(partial, 1);   // combine k-halves

        // tanh(z) = 1 - 2/(exp(2z)+1); saturates correctly at +/-inf.
        float z = x + bj + sum;
        float e = __expf(2.f * z);
        hn = 1.f - 2.f / (e + 1.f);

        if (q == 0)
            hbuf[cur ^ 1][j] = hn;                       // next h
        else
            ybf[(size_t)t * (BATCH * HID) + b * HID + j] = __float2bfloat16(hn);

        __syncthreads();   // next-h visible; also fences reads of hbuf[cur]
        cur ^= 1;
        x = xn;
    }
    if (q == 0) state_out[b * HID + j] = hn;
}

// ---------------------------------------------------------------------------
// Kernel 3: C[8192][10000] = Y_bf16 @ Wd^T_bf16 + b_d, f32 out. (unchanged)
// ---------------------------------------------------------------------------
__global__ void gemm_kernel(const __hip_bfloat16* __restrict__ A,   // [8192][256]
                            const __hip_bfloat16* __restrict__ BT,  // [10000][256]
                            const float* __restrict__ bd,
                            float* __restrict__ C) {
    const int n0 = blockIdx.x * 128;
    const int m0 = blockIdx.y * 128;
    const int tid = threadIdx.x;
    const int lane = tid & 63;
    const int wv = tid >> 6;
    const int wr = wv >> 1;
    const int wc = wv & 1;
    const int r15 = lane & 15;
    const int g = lane >> 4;

    __shared__ alignas(16) __hip_bfloat16 As[128][72];
    __shared__ alignas(16) __hip_bfloat16 Bs[128][72];

    f32x4 acc[4][4] = {};

    for (int kb = 0; kb < HID; kb += 64) {
        __syncthreads();
#pragma unroll
        for (int c = 0; c < 4; ++c) {
            int chunk = c * 256 + tid;
            int row = chunk >> 3;
            int cc = chunk & 7;
            bf16x8 av = *reinterpret_cast<const bf16x8*>(
                &A[(size_t)(m0 + row) * HID + kb + cc * 8]);
            *reinterpret_cast<bf16x8*>(&As[row][cc * 8]) = av;

            int nrow = n0 + row;
            bf16x8 bv;
#pragma unroll
            for (int e = 0; e < 8; ++e) bv[e] = (__bf16)0.f;
            if (nrow < VOCAB)
                bv = *reinterpret_cast<const bf16x8*>(
                    &BT[(size_t)nrow * HID + kb + cc * 8]);
            *reinterpret_cast<bf16x8*>(&Bs[row][cc * 8]) = bv;
        }
        __syncthreads();

#pragma unroll
        for (int kk = 0; kk < 64; kk += 32) {
            bf16x8 af[4], bfr[4];
#pragma unroll
            for (int m = 0; m < 4; ++m)
                af[m] = *reinterpret_cast<const bf16x8*>(
                    &As[wr * 64 + m * 16 + r15][kk + g * 8]);
#pragma unroll
            for (int n = 0; n < 4; ++n)
                bfr[n] = *reinterpret_cast<const bf16x8*>(
                    &Bs[wc * 64 + n * 16 + r15][kk + g * 8]);
#pragma unroll
            for (int m = 0; m < 4; ++m)
#pragma unroll
                for (int n = 0; n < 4; ++n)
                    acc[m][n] = __builtin_amdgcn_mfma_f32_16x16x32_bf16(
                        af[m], bfr[n], acc[m][n], 0, 0, 0);
        }
    }

#pragma unroll
    for (int m = 0; m < 4; ++m) {
        int rowb = m0 + wr * 64 + m * 16 + g * 4;
#pragma unroll
        for (int n = 0; n < 4; ++n) {
            int col = n0 + wc * 64 + n * 16 + r15;
            if (col < VOCAB) {
                float bias = bd[col];
#pragma unroll
                for (int r = 0; r < 4; ++r) {
                    C[(size_t)(rowb + r) * VOCAB + col] = acc[m][n][r] + bias;
                }
            }
        }
    }
}

// ---------------------------------------------------------------------------
extern "C" void kernel_launch(void* const* d_in, const int* in_sizes, int n_in,
                              void* d_out, int out_size, void* d_ws, size_t ws_size,
                              hipStream_t stream) {
    const int* tokens  = (const int*)d_in[0];
    const float* Wxh   = (const float*)d_in[1];
    const float* Whh   = (const float*)d_in[2];
    const float* bh    = (const float*)d_in[3];
    const float* Wd    = (const float*)d_in[4];
    const float* bd    = (const float*)d_in[5];
    const float* h0    = (const float*)d_in[6];

    float* out = (float*)d_out;
    float* state_out = out + (size_t)MROWS * VOCAB;

    __hip_bfloat16* ybf = (__hip_bfloat16*)d_ws;
    __hip_bfloat16* wdt = (__hip_bfloat16*)((char*)d_ws + (size_t)MROWS * HID * 2);

    hipLaunchKernelGGL(transpose_wd_kernel, dim3(157, 4), dim3(256), 0, stream,
                       Wd, wdt);
    hipLaunchKernelGGL(rnn_kernel, dim3(BATCH), dim3(512), 0, stream,
                       tokens, Wxh, Whh, bh, h0, ybf, state_out);
    hipLaunchKernelGGL(gemm_kernel, dim3(79, 64), dim3(256), 0, stream,
                       ybf, wdt, bd, out);
}

// Round 3
// 350.743 us; speedup vs baseline: 2.0642x; 1.1712x over previous
//
#include <hip/hip_runtime.h>
#include <hip/hip_bf16.h>

// Problem constants
#define VOCAB 10000
#define HID 256
#define BATCH 32
#define STEPS 256
#define MROWS (STEPS * BATCH)   // 8192

typedef __bf16 bf16x8 __attribute__((ext_vector_type(8)));
typedef float f32x4 __attribute__((ext_vector_type(4)));

// ---------------------------------------------------------------------------
// Kernel 1: transpose + convert W_d [256][10000] f32 -> WdT [10000][256] bf16
// ---------------------------------------------------------------------------
__global__ void transpose_wd_kernel(const float* __restrict__ Wd,
                                    __hip_bfloat16* __restrict__ WdT) {
    __shared__ __hip_bfloat16 tile[64][68];
    const int n0 = blockIdx.x * 64;
    const int k0 = blockIdx.y * 64;
    const int tid = threadIdx.x;
    const int lane = tid & 63;
    const int w = tid >> 6;

#pragma unroll
    for (int i = 0; i < 16; ++i) {
        int k = w * 16 + i;
        int n = lane;
        float v = (n0 + n < VOCAB) ? Wd[(size_t)(k0 + k) * VOCAB + n0 + n] : 0.f;
        tile[n][k] = __float2bfloat16(v);
    }
    __syncthreads();
#pragma unroll
    for (int i = 0; i < 16; ++i) {
        int n = w * 16 + i;
        int k = lane;
        if (n0 + n < VOCAB)
            WdT[(size_t)(n0 + n) * HID + k0 + k] = tile[n][k];
    }
}

// ---------------------------------------------------------------------------
// Kernel 2: gather + RNN recurrence, fp32.
// 32 blocks x 512 threads. Thread (j = tid>>1, q = tid&1) owns half of W_hh
// column j in registers. amdgpu_waves_per_eu(2,2) pins the scheduler's
// occupancy target to 2 waves/SIMD (VGPR budget 256) so the 128 weight loads
// are NOT sunk into the t-loop (round-2 failure mode: VGPR_Count=84 ->
// re-read 256KB/step from L2 = 2680 cy/step).
// h double-buffered in LDS, halves padded apart so the even/odd broadcast
// addresses hit different banks. One barrier per step.
// ---------------------------------------------------------------------------
#define HHALF 132   // 128 + 4 pad: q=1 base lands on bank 4, not bank 0

__global__ __launch_bounds__(512)
__attribute__((amdgpu_waves_per_eu(2, 2)))
void rnn_kernel(const int* __restrict__ tokens, const float* __restrict__ Wxh,
                const float* __restrict__ Whh, const float* __restrict__ bh,
                const float* __restrict__ h0, __hip_bfloat16* __restrict__ ybf,
                float* __restrict__ state_out) {
    const int b = blockIdx.x;
    const int tid = threadIdx.x;
    const int j = tid >> 1;      // output column 0..255
    const int q = tid & 1;       // k-half

    __shared__ alignas(16) float hbuf[2][2][HHALF];

    // Half-column of W_hh into registers: w[i] = Whh[q*128 + i][j].
    float w[128];
#pragma unroll
    for (int i = 0; i < 128; ++i)
        w[i] = Whh[(size_t)(q * 128 + i) * HID + j];

    if (q == 0) hbuf[0][j >> 7][j & 127] = h0[b * HID + j];
    const float bj = bh[j];
    const int* trow = tokens + b * STEPS;

    // Prefetch step-0 gathered x.
    float x = Wxh[(size_t)trow[0] * HID + j];
    __syncthreads();

    float hn = 0.f;
    int cur = 0;
    for (int t = 0; t < STEPS; ++t) {
        // Prefetch next step's x (hidden under the dot product).
        float xn = 0.f;
        if (t + 1 < STEPS)
            xn = Wxh[(size_t)trow[t + 1] * HID + j];

        const float* hrow = &hbuf[cur][q][0];
        float a0 = 0.f, a1 = 0.f, a2 = 0.f, a3 = 0.f;
#pragma unroll
        for (int i4 = 0; i4 < 32; ++i4) {
            float4 hv = *reinterpret_cast<const float4*>(&hrow[i4 * 4]);
            a0 += hv.x * w[i4 * 4 + 0];
            a1 += hv.y * w[i4 * 4 + 1];
            a2 += hv.z * w[i4 * 4 + 2];
            a3 += hv.w * w[i4 * 4 + 3];
        }
        float partial = (a0 + a1) + (a2 + a3);
        float sum = partial + __shfl_xor(partial, 1);   // combine k-halves

        // tanh(z) = 1 - 2/(exp(2z)+1)
        float z = x + bj + sum;
        float e = __expf(2.f * z);
        hn = 1.f - 2.f / (e + 1.f);

        if (q == 0)
            hbuf[cur ^ 1][j >> 7][j & 127] = hn;         // next h
        else
            ybf[(size_t)t * (BATCH * HID) + b * HID + j] = __float2bfloat16(hn);

        __syncthreads();
        cur ^= 1;
        x = xn;
    }
    if (q == 0) state_out[b * HID + j] = hn;
}

// ---------------------------------------------------------------------------
// Kernel 3: C[8192][10000] = Y_bf16 @ Wd^T_bf16 + b_d, f32 out.
// Operand-SWAPPED MFMA: acc[m][n] = mfma(bfr[n], af[m], .) so each lane's 4
// acc regs are 4 CONSECUTIVE vocab columns at fixed m -> f32x4 stores.
// (Empirical round-1 mapping: reg-dim <-> first operand's r15 index,
//  lane&15 <-> second operand's r15 index.)
// ---------------------------------------------------------------------------
__global__ void gemm_kernel(const __hip_bfloat16* __restrict__ A,   // [8192][256]
                            const __hip_bfloat16* __restrict__ BT,  // [10000][256]
                            const float* __restrict__ bd,
                            float* __restrict__ C) {
    const int n0 = blockIdx.x * 128;
    const int m0 = blockIdx.y * 128;
    const int tid = threadIdx.x;
    const int lane = tid & 63;
    const int wv = tid >> 6;
    const int wr = wv >> 1;
    const int wc = wv & 1;
    const int r15 = lane & 15;
    const int g = lane >> 4;

    __shared__ alignas(16) __hip_bfloat16 As[128][72];
    __shared__ alignas(16) __hip_bfloat16 Bs[128][72];

    f32x4 acc[4][4] = {};

    for (int kb = 0; kb < HID; kb += 64) {
        __syncthreads();
#pragma unroll
        for (int c = 0; c < 4; ++c) {
            int chunk = c * 256 + tid;
            int row = chunk >> 3;
            int cc = chunk & 7;
            bf16x8 av = *reinterpret_cast<const bf16x8*>(
                &A[(size_t)(m0 + row) * HID + kb + cc * 8]);
            *reinterpret_cast<bf16x8*>(&As[row][cc * 8]) = av;

            int nrow = n0 + row;
            bf16x8 bv;
#pragma unroll
            for (int e = 0; e < 8; ++e) bv[e] = (__bf16)0.f;
            if (nrow < VOCAB)
                bv = *reinterpret_cast<const bf16x8*>(
                    &BT[(size_t)nrow * HID + kb + cc * 8]);
            *reinterpret_cast<bf16x8*>(&Bs[row][cc * 8]) = bv;
        }
        __syncthreads();

#pragma unroll
        for (int kk = 0; kk < 64; kk += 32) {
            bf16x8 af[4], bfr[4];
#pragma unroll
            for (int m = 0; m < 4; ++m)
                af[m] = *reinterpret_cast<const bf16x8*>(
                    &As[wr * 64 + m * 16 + r15][kk + g * 8]);
#pragma unroll
            for (int n = 0; n < 4; ++n)
                bfr[n] = *reinterpret_cast<const bf16x8*>(
                    &Bs[wc * 64 + n * 16 + r15][kk + g * 8]);
#pragma unroll
            for (int m = 0; m < 4; ++m)
#pragma unroll
                for (int n = 0; n < 4; ++n)
                    acc[m][n] = __builtin_amdgcn_mfma_f32_16x16x32_bf16(
                        bfr[n], af[m], acc[m][n], 0, 0, 0);
        }
    }

    // Epilogue: element (reg r, lane) = C[m*16 + r15][n*16 + g*4 + r].
#pragma unroll
    for (int m = 0; m < 4; ++m) {
        int row = m0 + wr * 64 + m * 16 + r15;
#pragma unroll
        for (int n = 0; n < 4; ++n) {
            int cb = n0 + wc * 64 + n * 16;      // 16-col frag base
            if (cb + 15 < VOCAB) {               // VOCAB%16==0 -> all-or-nothing
                int col = cb + g * 4;
                float4 bv = *reinterpret_cast<const float4*>(&bd[col]);
                f32x4 v = acc[m][n];
                v[0] += bv.x; v[1] += bv.y; v[2] += bv.z; v[3] += bv.w;
                *reinterpret_cast<f32x4*>(&C[(size_t)row * VOCAB + col]) = v;
            }
        }
    }
}

// ---------------------------------------------------------------------------
extern "C" void kernel_launch(void* const* d_in, const int* in_sizes, int n_in,
                              void* d_out, int out_size, void* d_ws, size_t ws_size,
                              hipStream_t stream) {
    const int* tokens  = (const int*)d_in[0];
    const float* Wxh   = (const float*)d_in[1];
    const float* Whh   = (const float*)d_in[2];
    const float* bh    = (const float*)d_in[3];
    const float* Wd    = (const float*)d_in[4];
    const float* bd    = (const float*)d_in[5];
    const float* h0    = (const float*)d_in[6];

    float* out = (float*)d_out;
    float* state_out = out + (size_t)MROWS * VOCAB;

    __hip_bfloat16* ybf = (__hip_bfloat16*)d_ws;
    __hip_bfloat16* wdt = (__hip_bfloat16*)((char*)d_ws + (size_t)MROWS * HID * 2);

    hipLaunchKernelGGL(transpose_wd_kernel, dim3(157, 4), dim3(256), 0, stream,
                       Wd, wdt);
    hipLaunchKernelGGL(rnn_kernel, dim3(BATCH), dim3(512), 0, stream,
                       tokens, Wxh, Whh, bh, h0, ybf, state_out);
    hipLaunchKernelGGL(gemm_kernel, dim3(79, 64), dim3(256), 0, stream,
                       ybf, wdt, bd, out);
}